// Round 14
// baseline (46.792 us; speedup 1.0000x reference)
//
#include <hip/hip_runtime.h>
#include <hip/hip_bf16.h>

// LLoCaAttention, MI355X. Two-kernel structure:
//  1) rot_cast: rotation (blockdiag(1,Q^T)) + f32->bf16. K row-major [key][32]
//     (linear); V transposed+permuted+XOR-swizzled
//     (Vt[bh][128-chunk][32ch][16 granules ^ (ch&15)]).
//  2) lloca_attn: bf16 MFMA flash attention, split-K WITHIN the block:
//     8 waves; waves 0-3 do keys [0,1024), waves 4-7 do [1024,2048) for the
//     same 128 queries -> 4096 waves total = 4 waves/SIMD (2x R13) at
//     UNCHANGED per-pipe totals (each wave touches half the keys). m=0
//     softmax makes partials additive; merge via LDS in-block (no global
//     partials -- fixes R10's regression). Pipeline order per R13:
//     vmcnt(0) -> barrier -> STAGE(i+1) -> compute(i). BK=128/group,
//     LDS 64 KB/block = 2 blocks/CU.

#define NB 4
#define NH 8
#define NS 2048
#define NC 32

typedef float f32x4 __attribute__((ext_vector_type(4)));
typedef short s16x8 __attribute__((ext_vector_type(8)));
typedef short s16x4 __attribute__((ext_vector_type(4)));

// 1/(C * ln2): fold softmax 1/C scale and log2-domain conversion into Q.
#define QSCALE 0.04511260931463978f

__device__ __forceinline__ short f2bf(float f) {  // RTNE f32 -> bf16 bits
  union { float f; unsigned u; } c; c.f = f;
  return (short)((c.u + 0x7FFFu + ((c.u >> 16) & 1u)) >> 16);
}

__device__ __forceinline__ void gload16(const void* g, void* l) {
  // async global->LDS, 16 B/lane; LDS dst = wave-uniform base + lane*16.
  __builtin_amdgcn_global_load_lds(
      (const __attribute__((address_space(1))) unsigned int*)g,
      (__attribute__((address_space(3))) unsigned int*)l, 16, 0, 0);
}

__device__ __forceinline__ void load_Q3(const float* __restrict__ F, int b, int n,
                                        float q9[9]) {
  const float* p = F + ((size_t)(b * NS + n)) * 16 + 5;  // rows/cols 1..3 of 4x4
  q9[0] = p[0]; q9[1] = p[1]; q9[2] = p[2];
  q9[3] = p[4]; q9[4] = p[5]; q9[5] = p[6];
  q9[6] = p[8]; q9[7] = p[9]; q9[8] = p[10];
}

// spatial part (elements 1..3) <- Q^T * spatial   [input transform]
__device__ __forceinline__ void rotT(const float q9[9], f32x4& v) {
  const float x = v[1], y = v[2], z = v[3];
  v[1] = q9[0] * x + q9[3] * y + q9[6] * z;
  v[2] = q9[1] * x + q9[4] * y + q9[7] * z;
  v[3] = q9[2] * x + q9[5] * y + q9[8] * z;
}

// spatial part <- Q * spatial     [output transform]
__device__ __forceinline__ void rotF(const float q9[9], f32x4& v) {
  const float x = v[1], y = v[2], z = v[3];
  v[1] = q9[0] * x + q9[1] * y + q9[2] * z;
  v[2] = q9[3] * x + q9[4] * y + q9[5] * z;
  v[3] = q9[6] * x + q9[7] * y + q9[8] * z;
}

// ---- pass 1: rotate + cast. gid<65536: K rows. gid>=65536: V key-quads. ----
__launch_bounds__(256)
__global__ void rot_cast(const float* __restrict__ Kg,
                         const float* __restrict__ Vg,
                         const float* __restrict__ Fg,
                         unsigned short* __restrict__ Kbf,
                         unsigned short* __restrict__ Vt) {
  const int gid = blockIdx.x * 256 + threadIdx.x;  // 65536 + 16384 threads
  if (gid < 65536) {
    // K: one particle row, row-major bf16 out.
    const int r = gid;                    // (b*H + h)*N + n
    const int n = r & (NS - 1);
    const int b = r >> 14;
    const float* p = Kg + (size_t)r * NC;
    f32x4 c[8];
#pragma unroll
    for (int i = 0; i < 8; i++) c[i] = *(const f32x4*)(p + 4 * i);
    float q9[9]; load_Q3(Fg, b, n, q9);
#pragma unroll
    for (int i = 4; i < 8; i++) rotT(q9, c[i]);   // four-vectors (ch 16..31)
    unsigned short* o = Kbf + (size_t)r * NC;
#pragma unroll
    for (int i = 0; i < 8; i += 2) {
      s16x8 w;
#pragma unroll
      for (int e = 0; e < 4; e++) {
        w[e]     = f2bf(c[i][e]);
        w[4 + e] = f2bf(c[i + 1][e]);
      }
      *(s16x8*)(o + 4 * i) = w;
    }
  } else {
    // V: one key-quad (4 particles) -> transposed+permuted+swizzled layout:
    // logical pos(c in 32-group) = grp*32 + newsub*4 + (c&3); the 16B granule
    // (pos>>3) is stored at (pos>>3) ^ (ch&15)  [read applies the same XOR].
    const int r  = gid - 65536;           // 0..16383 quads
    const int bh = r >> 9;                // 512 quads per bh
    const int b  = bh >> 3;
    const int K0 = (r & 511) << 2;        // first key of quad
    const float* vsrc = Vg + ((size_t)bh * NS + K0) * NC;
    s16x4 outc[32];
#pragma unroll
    for (int k = 0; k < 4; k++) {
      f32x4 c[8];
#pragma unroll
      for (int i = 0; i < 8; i++) c[i] = *(const f32x4*)(vsrc + (size_t)k * NC + 4 * i);
      float q9[9]; load_Q3(Fg, b, K0 + k, q9);
#pragma unroll
      for (int i = 4; i < 8; i++) rotT(q9, c[i]);
#pragma unroll
      for (int i = 0; i < 8; i++)
#pragma unroll
        for (int e = 0; e < 4; e++) outc[i * 4 + e][k] = f2bf(c[i][e]);
    }
    const int cg     = K0 & 31;
    const int sub4   = cg >> 2;
    const int newsub = (sub4 & 3) * 2 + (sub4 >> 2);
    const int pos    = ((K0 & 127) >> 5) * 32 + newsub * 4;
    const int gpos   = pos >> 3;          // 16B granule index 0..15
    const int rem    = pos & 7;           // 0 or 4
    unsigned short* ob = Vt + (size_t)bh * (NS * NC) + ((K0 >> 7) & 15) * 4096;
#pragma unroll
    for (int ch = 0; ch < 32; ch++)
      *(s16x4*)(ob + ch * 128 + ((gpos ^ (ch & 15)) << 3) + rem) = outc[ch];
  }
}

// ---- pass 2: flash attention, in-block split-K, async gload_lds staging ----
__launch_bounds__(512, 4)
__global__ void lloca_attn(const float* __restrict__ Qg,
                           const unsigned short* __restrict__ Kbf,
                           const unsigned short* __restrict__ Vt,
                           const float* __restrict__ Fg,
                           float* __restrict__ Og) {
  // Per key-group (grp=0,1): double-buffered BK=128 tiles, linear layouts.
  // K: [128 keys][32 ch]; V: [32 ch][128 keys swizzled]. 64 KB total.
  __shared__ __align__(16) unsigned short Klds[2][2][128 * 32];  // [grp][buf]
  __shared__ __align__(16) unsigned short Vlds[2][2][32 * 128];

  const int tid  = threadIdx.x;   // 0..511 (8 waves)
  const int lane = tid & 63;
  const int wv   = tid >> 6;
  const int grp  = wv >> 2;     // key-split group: 0 -> keys [0,1024), 1 -> [1024,2048)
  const int lwv  = wv & 3;      // wave within group
  const int g    = lane >> 4;   // lane group 0..3
  const int lq   = lane & 15;   // query-within-tile (MFMA col)

  const int blk = blockIdx.x;   // 512 = B(2b) H(3b) qb(4b)
  const int b   = blk >> 7;
  const int h   = (blk >> 4) & 7;
  const int qb  = blk & 15;

  const size_t bhr = (size_t)(b * NH + h) * NS;
  // group key base: 1024 keys = 32768 ush for both K (row-major) and Vt (chunked)
  const unsigned short* Kp  = Kbf + bhr * NC + grp * 32768;
  const unsigned short* Vtp = Vt  + bhr * NC + grp * 32768;
  float*                Op  = Og  + bhr * NC;

  const int qbase = qb * 128 + lwv * 32;  // this wave's 32 queries (2 tiles of 16)

  const f32x4 zero4 = {0.f, 0.f, 0.f, 0.f};
  const short ONE = (short)0x3F80;  // bf16 1.0
  const s16x8 ones8 = {ONE, ONE, ONE, ONE, ONE, ONE, ONE, ONE};

  // ---- prologue: load + rotate + scale + pack own Q fragments ----
  s16x8 qfrag[2];
  f32x4 acc[2][2];
  f32x4 accL[2];
#pragma unroll
  for (int t = 0; t < 2; t++) {
    const int qi = qbase + t * 16 + lq;
    const float* qp = Qg + (bhr + qi) * NC + g * 8;  // slot (g,j) <-> ch 8g+j
    f32x4 a = *(const f32x4*)qp;
    f32x4 c = *(const f32x4*)(qp + 4);
    if (g >= 2) {  // g==2: vectors 0,1 ; g==3: vectors 2,3
      float q9[9]; load_Q3(Fg, b, qi, q9);
      rotT(q9, a);
      rotT(q9, c);
    }
#pragma unroll
    for (int e = 0; e < 4; e++) {
      qfrag[t][e]     = f2bf(a[e] * QSCALE);
      qfrag[t][4 + e] = f2bf(c[e] * QSCALE);
    }
    acc[t][0] = zero4;
    acc[t][1] = zero4;
    accL[t]   = zero4;
  }

  // staging: per 128-key tile each group's 4 waves DMA 8 KB K + 8 KB V
  // (4 gload16/wave, 1 KB wave-wide each). Linear copies of 4096-ush tiles.
  const int lel = lane * 8;

#define STAGE(buf, i)                                                          \
  do {                                                                         \
    const size_t goff = (size_t)(i) * 4096;                                    \
    const unsigned short* ks = Kp + goff + lwv * 1024 + lel;                   \
    const unsigned short* vs = Vtp + goff + lwv * 1024 + lel;                  \
    unsigned short* kd = &Klds[grp][buf][lwv * 1024];                          \
    unsigned short* vd = &Vlds[grp][buf][lwv * 1024];                          \
    gload16(ks, kd); gload16(ks + 512, kd + 512);                              \
    gload16(vs, vd); gload16(vs + 512, vd + 512);                              \
  } while (0)

  STAGE(0, 0);

  const int NTT = 1024 / 128;  // 8 tiles per group
  for (int i = 0; i < NTT; i++) {
    const int cur = i & 1;
    // wait MY tile-i DMAs (only ones in flight; had a full compute to land),
    // then barrier: every wave drained its own share -> tile i fully resident.
    asm volatile("s_waitcnt vmcnt(0)" ::: "memory");
    __builtin_amdgcn_s_barrier();
    __builtin_amdgcn_sched_barrier(0);  // keep ds_reads below the barrier
    if (i + 1 < NTT) STAGE(cur ^ 1, i + 1);  // flies across compute(i)
    __builtin_amdgcn_s_setprio(1);
#pragma unroll
    for (int kgi = 0; kgi < 4; kgi++) {
      const int kgb = kgi * 32;
      const s16x8 kf0 = *(const s16x8*)&Klds[grp][cur][(kgb + lq) * 32 + g * 8];
      const s16x8 kf1 = *(const s16x8*)&Klds[grp][cur][(kgb + 16 + lq) * 32 + g * 8];
      const int vsw = (((kgb >> 3) + g) ^ lq) << 3;  // granule XOR swizzle
      const s16x8 va0 = *(const s16x8*)&Vlds[grp][cur][lq * 128 + vsw];
      const s16x8 va1 = *(const s16x8*)&Vlds[grp][cur][(16 + lq) * 128 + vsw];
#pragma unroll
      for (int t = 0; t < 2; t++) {
        // S^T = K_chunk * Q : lane holds scores for q=lq, keys kgb+4g+r / kgb+16+4g+r
        f32x4 s0 = __builtin_amdgcn_mfma_f32_16x16x32_bf16(kf0, qfrag[t], zero4, 0, 0, 0);
        f32x4 s1 = __builtin_amdgcn_mfma_f32_16x16x32_bf16(kf1, qfrag[t], zero4, 0, 0, 0);
        // m = 0 fixed: scores are q.k/C in log2 units; f32 exp2 overflow-safe.
        float p0 = __builtin_amdgcn_exp2f(s0[0]);
        float p1 = __builtin_amdgcn_exp2f(s0[1]);
        float p2 = __builtin_amdgcn_exp2f(s0[2]);
        float p3 = __builtin_amdgcn_exp2f(s0[3]);
        float p4 = __builtin_amdgcn_exp2f(s1[0]);
        float p5 = __builtin_amdgcn_exp2f(s1[1]);
        float p6 = __builtin_amdgcn_exp2f(s1[2]);
        float p7 = __builtin_amdgcn_exp2f(s1[3]);
        union { __hip_bfloat162 h2v[4]; s16x8 v; } pk;
        pk.h2v[0] = __float22bfloat162_rn(make_float2(p0, p1));
        pk.h2v[1] = __float22bfloat162_rn(make_float2(p2, p3));
        pk.h2v[2] = __float22bfloat162_rn(make_float2(p4, p5));
        pk.h2v[3] = __float22bfloat162_rn(make_float2(p6, p7));
        // l-sum on the matrix pipe: every C row of (ones * P) = sum_k P[k][lq]
        accL[t]   = __builtin_amdgcn_mfma_f32_16x16x32_bf16(ones8, pk.v, accL[t], 0, 0, 0);
        acc[t][0] = __builtin_amdgcn_mfma_f32_16x16x32_bf16(va0,   pk.v, acc[t][0], 0, 0, 0);
        acc[t][1] = __builtin_amdgcn_mfma_f32_16x16x32_bf16(va1,   pk.v, acc[t][1], 0, 0, 0);
      }
    }
    __builtin_amdgcn_s_setprio(0);
  }

  // ---- merge the two key-groups via LDS (partials are additive: m=0), then
  // normalize, rotate output vector g by Q_query, store.
  __syncthreads();  // all compute done; K/V tiles dead from here
  float* M = (float*)&Klds[0][0][0];   // [128 q][32 ch] f32 = 16 KB
  float* L = M + 128 * 32;             // [128 q] f32 (spills into Klds[1] space)
  if (grp) {
#pragma unroll
    for (int t = 0; t < 2; t++) {
      const int q = lwv * 32 + t * 16 + lq;
      *(f32x4*)&M[q * 32 + 4 * g]      = acc[t][0];
      *(f32x4*)&M[q * 32 + 16 + 4 * g] = acc[t][1];
      L[q] = accL[t][0];  // 4 g-lanes write the same value (benign)
    }
  }
  __syncthreads();
  if (!grp) {
#pragma unroll
    for (int t = 0; t < 2; t++) {
      const int q  = lwv * 32 + t * 16 + lq;
      const int qi = qb * 128 + q;
      const float inv = 1.0f / (accL[t][0] + L[q]);
      f32x4 o0 = (acc[t][0] + *(const f32x4*)&M[q * 32 + 4 * g]) * inv;
      f32x4 o1 = (acc[t][1] + *(const f32x4*)&M[q * 32 + 16 + 4 * g]) * inv;
      float q9[9]; load_Q3(Fg, b, qi, q9);
      rotF(q9, o1);
      float* op = Op + (size_t)qi * NC;
      *(f32x4*)(op + g * 4)      = o0;
      *(f32x4*)(op + 16 + g * 4) = o1;
    }
  }
}

extern "C" void kernel_launch(void* const* d_in, const int* in_sizes, int n_in,
                              void* d_out, int out_size, void* d_ws, size_t ws_size,
                              hipStream_t stream) {
  (void)in_sizes; (void)n_in; (void)ws_size; (void)out_size;
  const float* q = (const float*)d_in[0];
  const float* k = (const float*)d_in[1];
  const float* v = (const float*)d_in[2];
  const float* f = (const float*)d_in[3];
  float* o = (float*)d_out;

  const size_t NEL = (size_t)NB * NH * NS * NC;  // 2,097,152 elements
  unsigned short* kbf = (unsigned short*)d_ws;   // 4 MB
  unsigned short* vt  = kbf + NEL;               // 4 MB

  // 65536 K-row threads + 16384 V-quad threads = 320 blocks of 256
  hipLaunchKernelGGL(rot_cast, dim3(320), dim3(256), 0, stream,
                     k, v, f, kbf, vt);
  hipLaunchKernelGGL(lloca_attn, dim3(512), dim3(512), 0, stream,
                     q, kbf, vt, f, o);
}

// Round 15
// 40.169 us; speedup vs baseline: 1.1649x; 1.1649x over previous
//
#include <hip/hip_runtime.h>
#include <hip/hip_bf16.h>

// LLoCaAttention, MI355X. Two-kernel structure:
//  1) rot_cast: rotation (blockdiag(1,Q^T)) + f32->bf16.
//     K: [key][32 ch] with GRANULE XOR SWIZZLE: 16B granule gi of key n is
//        stored at gi ^ (n&3). (R12/R13's linear layout was an 8-way bank
//        conflict on the kf ds_read_b128: bank-group (4lq+g) mod 8 covers
//        only 2 groups per lane-quarter. With the XOR: (4lq + g^(lq&3)) mod 8
//        -> 2 lanes/group = free.)
//     V: transposed+permuted+XOR-swizzled (granule ^ (ch&15)), as R13.
//  2) lloca_attn: bf16 MFMA flash attention, async gload_lds staging,
//     R13 pipeline order: vmcnt(0) -> barrier -> STAGE(i+1) -> compute(i).
//     BK=256, NT=2, 4-wave blocks, grid 512 (XCD-swizzled), m=0 softmax,
//     ones-MFMA l-sum.

#define NB 4
#define NH 8
#define NS 2048
#define NC 32

typedef float f32x4 __attribute__((ext_vector_type(4)));
typedef short s16x8 __attribute__((ext_vector_type(8)));
typedef short s16x4 __attribute__((ext_vector_type(4)));

// 1/(C * ln2): fold softmax 1/C scale and log2-domain conversion into Q.
#define QSCALE 0.04511260931463978f

__device__ __forceinline__ short f2bf(float f) {  // RTNE f32 -> bf16 bits
  union { float f; unsigned u; } c; c.f = f;
  return (short)((c.u + 0x7FFFu + ((c.u >> 16) & 1u)) >> 16);
}

__device__ __forceinline__ void gload16(const void* g, void* l) {
  // async global->LDS, 16 B/lane; LDS dst = wave-uniform base + lane*16.
  __builtin_amdgcn_global_load_lds(
      (const __attribute__((address_space(1))) unsigned int*)g,
      (__attribute__((address_space(3))) unsigned int*)l, 16, 0, 0);
}

__device__ __forceinline__ void load_Q3(const float* __restrict__ F, int b, int n,
                                        float q9[9]) {
  const float* p = F + ((size_t)(b * NS + n)) * 16 + 5;  // rows/cols 1..3 of 4x4
  q9[0] = p[0]; q9[1] = p[1]; q9[2] = p[2];
  q9[3] = p[4]; q9[4] = p[5]; q9[5] = p[6];
  q9[6] = p[8]; q9[7] = p[9]; q9[8] = p[10];
}

// spatial part (elements 1..3) <- Q^T * spatial   [input transform]
__device__ __forceinline__ void rotT(const float q9[9], f32x4& v) {
  const float x = v[1], y = v[2], z = v[3];
  v[1] = q9[0] * x + q9[3] * y + q9[6] * z;
  v[2] = q9[1] * x + q9[4] * y + q9[7] * z;
  v[3] = q9[2] * x + q9[5] * y + q9[8] * z;
}

// spatial part <- Q * spatial     [output transform]
__device__ __forceinline__ void rotF(const float q9[9], f32x4& v) {
  const float x = v[1], y = v[2], z = v[3];
  v[1] = q9[0] * x + q9[1] * y + q9[2] * z;
  v[2] = q9[3] * x + q9[4] * y + q9[5] * z;
  v[3] = q9[6] * x + q9[7] * y + q9[8] * z;
}

// ---- pass 1: rotate + cast. gid<65536: K rows. gid>=65536: V key-quads. ----
__launch_bounds__(256)
__global__ void rot_cast(const float* __restrict__ Kg,
                         const float* __restrict__ Vg,
                         const float* __restrict__ Fg,
                         unsigned short* __restrict__ Kbf,
                         unsigned short* __restrict__ Vt) {
  const int gid = blockIdx.x * 256 + threadIdx.x;  // 65536 + 16384 threads
  if (gid < 65536) {
    // K: one particle row; granule gi -> slot gi ^ (n&3) within the row.
    const int r = gid;                    // (b*H + h)*N + n
    const int n = r & (NS - 1);
    const int b = r >> 14;
    const float* p = Kg + (size_t)r * NC;
    f32x4 c[8];
#pragma unroll
    for (int i = 0; i < 8; i++) c[i] = *(const f32x4*)(p + 4 * i);
    float q9[9]; load_Q3(Fg, b, n, q9);
#pragma unroll
    for (int i = 4; i < 8; i++) rotT(q9, c[i]);   // four-vectors (ch 16..31)
    unsigned short* o = Kbf + (size_t)r * NC;
    const int ks = n & 3;
#pragma unroll
    for (int i = 0; i < 8; i += 2) {
      s16x8 w;
#pragma unroll
      for (int e = 0; e < 4; e++) {
        w[e]     = f2bf(c[i][e]);
        w[4 + e] = f2bf(c[i + 1][e]);
      }
      *(s16x8*)(o + (((i >> 1) ^ ks) << 3)) = w;
    }
  } else {
    // V: one key-quad (4 particles) -> transposed+permuted+swizzled layout:
    // logical pos(c in 32-group) = grp*32 + newsub*4 + (c&3); the 16B granule
    // (pos>>3) is stored at (pos>>3) ^ (ch&15)  [read applies the same XOR].
    const int r  = gid - 65536;           // 0..16383 quads
    const int bh = r >> 9;                // 512 quads per bh
    const int b  = bh >> 3;
    const int K0 = (r & 511) << 2;        // first key of quad
    const float* vsrc = Vg + ((size_t)bh * NS + K0) * NC;
    s16x4 outc[32];
#pragma unroll
    for (int k = 0; k < 4; k++) {
      f32x4 c[8];
#pragma unroll
      for (int i = 0; i < 8; i++) c[i] = *(const f32x4*)(vsrc + (size_t)k * NC + 4 * i);
      float q9[9]; load_Q3(Fg, b, K0 + k, q9);
#pragma unroll
      for (int i = 4; i < 8; i++) rotT(q9, c[i]);
#pragma unroll
      for (int i = 0; i < 8; i++)
#pragma unroll
        for (int e = 0; e < 4; e++) outc[i * 4 + e][k] = f2bf(c[i][e]);
    }
    const int cg     = K0 & 31;
    const int sub4   = cg >> 2;
    const int newsub = (sub4 & 3) * 2 + (sub4 >> 2);
    const int pos    = ((K0 & 127) >> 5) * 32 + newsub * 4;
    const int gpos   = pos >> 3;          // 16B granule index 0..15
    const int rem    = pos & 7;           // 0 or 4
    unsigned short* ob = Vt + (size_t)bh * (NS * NC) + ((K0 >> 7) & 15) * 4096;
#pragma unroll
    for (int ch = 0; ch < 32; ch++)
      *(s16x4*)(ob + ch * 128 + ((gpos ^ (ch & 15)) << 3) + rem) = outc[ch];
  }
}

// ---- pass 2: flash attention, pipelined async gload_lds staging ----
__launch_bounds__(256, 2)
__global__ void lloca_attn(const float* __restrict__ Qg,
                           const unsigned short* __restrict__ Kbf,
                           const unsigned short* __restrict__ Vt,
                           const float* __restrict__ Fg,
                           float* __restrict__ Og) {
  // Linear (DMA-filled) double-buffered BK=256 tiles.
  // K: [256 keys][32 ch, granule-swizzled]. V: [chunk][32 ch][128 swizzled].
  __shared__ __align__(16) unsigned short Klds[2][256 * 32];      // 16 KB each
  __shared__ __align__(16) unsigned short Vlds[2][2 * 32 * 128];  // 16 KB each

  const int tid  = threadIdx.x;   // 0..255 (4 waves)
  const int lane = tid & 63;
  const int wv   = tid >> 6;
  const int g    = lane >> 4;   // lane group 0..3
  const int lq   = lane & 15;   // query-within-tile (MFMA col)

  // XCD swizzle: XCD x gets works [x*64, x*64+64) = 4 bh -> 2 MB ⊂ its L2.
  const int bid = blockIdx.x;   // 512
  const int blk = (bid & 7) * 64 + (bid >> 3);
  const int b   = blk >> 7;
  const int h   = (blk >> 4) & 7;
  const int qb  = blk & 15;

  const size_t bhr = (size_t)(b * NH + h) * NS;
  const unsigned short* Kp  = Kbf + bhr * NC;
  const unsigned short* Vtp = Vt  + bhr * NC;
  float*                Op  = Og  + bhr * NC;

  const int qbase = qb * 128 + wv * 32;  // this wave's 32 queries (2 tiles of 16)

  const f32x4 zero4 = {0.f, 0.f, 0.f, 0.f};
  const short ONE = (short)0x3F80;  // bf16 1.0
  const s16x8 ones8 = {ONE, ONE, ONE, ONE, ONE, ONE, ONE, ONE};

  // ---- prologue: load + rotate + scale + pack own Q fragments ----
  s16x8 qfrag[2];
  f32x4 acc[2][2];
  f32x4 accL[2];
#pragma unroll
  for (int t = 0; t < 2; t++) {
    const int qi = qbase + t * 16 + lq;
    const float* qp = Qg + (bhr + qi) * NC + g * 8;  // slot (g,j) <-> ch 8g+j
    f32x4 a = *(const f32x4*)qp;
    f32x4 c = *(const f32x4*)(qp + 4);
    if (g >= 2) {  // g==2: vectors 0,1 ; g==3: vectors 2,3
      float q9[9]; load_Q3(Fg, b, qi, q9);
      rotT(q9, a);
      rotT(q9, c);
    }
#pragma unroll
    for (int e = 0; e < 4; e++) {
      qfrag[t][e]     = f2bf(a[e] * QSCALE);
      qfrag[t][4 + e] = f2bf(c[e] * QSCALE);
    }
    acc[t][0] = zero4;
    acc[t][1] = zero4;
    accL[t]   = zero4;
  }

  // staging: per 256-key tile each wave DMAs 4 KB of K and 4 KB of V
  // (8 gload16, 1 KB wave-wide each). Linear copies of 8192-ush tiles.
  const int lel = lane * 8;

#define STAGE(buf, i)                                                          \
  do {                                                                         \
    const size_t goff = (size_t)(i) * 8192;                                    \
    const unsigned short* ks = Kp + goff + wv * 2048 + lel;                    \
    const unsigned short* vs = Vtp + goff + wv * 2048 + lel;                   \
    unsigned short* kd = &Klds[buf][wv * 2048];                                \
    unsigned short* vd = &Vlds[buf][wv * 2048];                                \
    gload16(ks, kd);               gload16(ks + 512, kd + 512);                \
    gload16(ks + 1024, kd + 1024); gload16(ks + 1536, kd + 1536);              \
    gload16(vs, vd);               gload16(vs + 512, vd + 512);                \
    gload16(vs + 1024, vd + 1024); gload16(vs + 1536, vd + 1536);              \
  } while (0)

  STAGE(0, 0);

  const int ksw = (g ^ (lq & 3)) << 3;  // K granule un-swizzle for this lane

  const int NTT = NS / 256;  // 8 tiles
  for (int i = 0; i < NTT; i++) {
    const int cur = i & 1;
    // wait MY tile-i DMAs (only ones in flight; had a full compute to land),
    // then barrier: every wave drained its own share -> tile i fully resident.
    asm volatile("s_waitcnt vmcnt(0)" ::: "memory");
    __builtin_amdgcn_s_barrier();
    __builtin_amdgcn_sched_barrier(0);  // keep ds_reads below the barrier
    if (i + 1 < NTT) STAGE(cur ^ 1, i + 1);  // flies across compute(i)
    __builtin_amdgcn_s_setprio(1);
#pragma unroll
    for (int kgi = 0; kgi < 8; kgi++) {
      const int kgb = kgi * 32;
      const s16x8 kf0 = *(const s16x8*)&Klds[cur][(kgb + lq) * 32 + ksw];
      const s16x8 kf1 = *(const s16x8*)&Klds[cur][(kgb + 16 + lq) * 32 + ksw];
      const int vbase2 = (kgb >> 7) * 4096;        // 128-key chunk
      const int kgb7   = kgb & 127;
      const int vsw    = ((((kgb7) >> 3) + g) ^ lq) << 3;  // granule XOR swizzle
      const s16x8 va0 = *(const s16x8*)&Vlds[cur][vbase2 + lq * 128 + vsw];
      const s16x8 va1 = *(const s16x8*)&Vlds[cur][vbase2 + (16 + lq) * 128 + vsw];
#pragma unroll
      for (int t = 0; t < 2; t++) {
        // S^T = K_chunk * Q : lane holds scores for q=lq, keys kgb+4g+r / kgb+16+4g+r
        f32x4 s0 = __builtin_amdgcn_mfma_f32_16x16x32_bf16(kf0, qfrag[t], zero4, 0, 0, 0);
        f32x4 s1 = __builtin_amdgcn_mfma_f32_16x16x32_bf16(kf1, qfrag[t], zero4, 0, 0, 0);
        // m = 0 fixed: scores are q.k/C in log2 units; f32 exp2 overflow-safe.
        float p0 = __builtin_amdgcn_exp2f(s0[0]);
        float p1 = __builtin_amdgcn_exp2f(s0[1]);
        float p2 = __builtin_amdgcn_exp2f(s0[2]);
        float p3 = __builtin_amdgcn_exp2f(s0[3]);
        float p4 = __builtin_amdgcn_exp2f(s1[0]);
        float p5 = __builtin_amdgcn_exp2f(s1[1]);
        float p6 = __builtin_amdgcn_exp2f(s1[2]);
        float p7 = __builtin_amdgcn_exp2f(s1[3]);
        union { __hip_bfloat162 h2v[4]; s16x8 v; } pk;
        pk.h2v[0] = __float22bfloat162_rn(make_float2(p0, p1));
        pk.h2v[1] = __float22bfloat162_rn(make_float2(p2, p3));
        pk.h2v[2] = __float22bfloat162_rn(make_float2(p4, p5));
        pk.h2v[3] = __float22bfloat162_rn(make_float2(p6, p7));
        // l-sum on the matrix pipe: every C row of (ones * P) = sum_k P[k][lq]
        accL[t]   = __builtin_amdgcn_mfma_f32_16x16x32_bf16(ones8, pk.v, accL[t], 0, 0, 0);
        acc[t][0] = __builtin_amdgcn_mfma_f32_16x16x32_bf16(va0,   pk.v, acc[t][0], 0, 0, 0);
        acc[t][1] = __builtin_amdgcn_mfma_f32_16x16x32_bf16(va1,   pk.v, acc[t][1], 0, 0, 0);
      }
    }
    __builtin_amdgcn_s_setprio(0);
  }

  // ---- epilogue: normalize, rotate output vector g by Q_query, store.
  // O^T: col=q=lq, rows: ch 4g+r (acc0, scalars) / 16+4g+r (acc1, four-vector g)
#pragma unroll
  for (int t = 0; t < 2; t++) {
    const float inv = 1.0f / accL[t][0];
    const int qi = qbase + t * 16 + lq;
    float* op = Op + (size_t)qi * NC;
    f32x4 o0, o1;
#pragma unroll
    for (int r = 0; r < 4; r++) {
      o0[r] = acc[t][0][r] * inv;
      o1[r] = acc[t][1][r] * inv;
    }
    float q9[9]; load_Q3(Fg, b, qi, q9);
    rotF(q9, o1);
    *(f32x4*)(op + g * 4)      = o0;
    *(f32x4*)(op + 16 + g * 4) = o1;
  }
}

extern "C" void kernel_launch(void* const* d_in, const int* in_sizes, int n_in,
                              void* d_out, int out_size, void* d_ws, size_t ws_size,
                              hipStream_t stream) {
  (void)in_sizes; (void)n_in; (void)ws_size; (void)out_size;
  const float* q = (const float*)d_in[0];
  const float* k = (const float*)d_in[1];
  const float* v = (const float*)d_in[2];
  const float* f = (const float*)d_in[3];
  float* o = (float*)d_out;

  const size_t NEL = (size_t)NB * NH * NS * NC;  // 2,097,152 elements
  unsigned short* kbf = (unsigned short*)d_ws;   // 4 MB
  unsigned short* vt  = kbf + NEL;               // 4 MB

  // 65536 K-row threads + 16384 V-quad threads = 320 blocks of 256
  hipLaunchKernelGGL(rot_cast, dim3(320), dim3(256), 0, stream,
                     k, v, f, kbf, vt);
  hipLaunchKernelGGL(lloca_attn, dim3(512), dim3(256), 0, stream,
                     q, kbf, vt, f, o);
}